// Round 7
// baseline (851.721 us; speedup 1.0000x reference)
//
#include <hip/hip_runtime.h>
#include <hip/hip_bf16.h>

#define NN 50000
#define NE 500000
#define HID 128
#define LAYERS 3
#define RELS 8
#define BASES 30
#define GRAPHS 16
#define CLASSES 8
#define EPSV 1e-5f
#define KTOT (HID * (RELS + 1))       // 1152 = GEMM K
#define NDR (NN * RELS)               // 400000 (relation-major buckets)
#define SCAN_CHUNK 1024
#define NBLK_DR ((NDR + SCAN_CHUNK - 1) / SCAN_CHUNK)   // 391
#define PCHUNK 128

typedef __attribute__((ext_vector_type(8))) short short8;   // 8 bf16 (4 VGPRs)
typedef __attribute__((ext_vector_type(4))) float f32x4;    // MFMA accumulator

__device__ __forceinline__ float bf2f(unsigned short u) {
    union { unsigned int i; float f; } x; x.i = ((unsigned int)u) << 16; return x.f;
}
__device__ __forceinline__ unsigned short f2bf(float f) {
    __hip_bfloat16 b = __float2bfloat16(f);
    return *(unsigned short*)&b;
}

// ---------------- wT2: [L][128 n][1152 k] bf16, wT2[l][n][k] = B[k][n]
// k<128: root[l][k][n]; k=128+r*128+kk: sum_b comp[l][r][b]*basis[l][b][kk][n]
__global__ void build_wcat(const float* __restrict__ basis, const float* __restrict__ comp,
                           const float* __restrict__ root, unsigned short* __restrict__ wT2) {
    int idx = blockIdx.x * blockDim.x + threadIdx.x;
    if (idx >= LAYERS * HID * KTOT) return;
    int k = idx % KTOT;
    int rest = idx / KTOT;
    int n = rest & (HID - 1);
    int l = rest >> 7;
    float v;
    if (k < HID) {
        v = root[((size_t)l * HID + k) * HID + n];
    } else {
        int r = (k - HID) >> 7;
        int kk = (k - HID) & (HID - 1);
        const float* cp = comp + ((size_t)l * RELS + r) * BASES;
        float s = 0.f;
        for (int b = 0; b < BASES; ++b)
            s += cp[b] * basis[(((size_t)(l * BASES + b)) * HID + kk) * HID + n];
        v = s;
    }
    wT2[idx] = f2bf(v);
}

// ---------------- BN1 (eval mode) -> bf16
__global__ void bn1_kernel(const float* __restrict__ x, const float* __restrict__ gamma,
                           const float* __restrict__ beta, const float* __restrict__ mean,
                           const float* __restrict__ var, unsigned short* __restrict__ habf) {
    int idx = blockIdx.x * blockDim.x + threadIdx.x;
    if (idx >= NN * HID) return;
    int f = idx & (HID - 1);
    habf[idx] = f2bf((x[idx] - mean[f]) * rsqrtf(var[f] + EPSV) * gamma[f] + beta[f]);
}

// ---------------- count per (rel, dst) bucket (relation-major)
__global__ void deg_kernel(const int* __restrict__ ei, const int* __restrict__ ea,
                           int* __restrict__ cntb) {
    int e = blockIdx.x * blockDim.x + threadIdx.x;
    if (e >= NE) return;
    int dst = ei[NE + e];
    atomicAdd(&cntb[ea[e] * NN + dst], 1);
}

// ---------------- exclusive scan of cntb[NDR] -> rowptr_r
__global__ __launch_bounds__(256) void scan_partial(const int* __restrict__ cnt,
                                                    int* __restrict__ rowptr,
                                                    int* __restrict__ bsum) {
    __shared__ int ssc[256];
    int t = threadIdx.x;
    int base = blockIdx.x * SCAN_CHUNK + t * 4;
    int v[4];
#pragma unroll
    for (int j = 0; j < 4; ++j) v[j] = (base + j < NDR) ? cnt[base + j] : 0;
    int tsum = v[0] + v[1] + v[2] + v[3];
    ssc[t] = tsum;
    __syncthreads();
    for (int ofs = 1; ofs < 256; ofs <<= 1) {
        int add = (t >= ofs) ? ssc[t - ofs] : 0;
        __syncthreads();
        ssc[t] += add;
        __syncthreads();
    }
    int excl = ssc[t] - tsum;
    int e = 0;
#pragma unroll
    for (int j = 0; j < 4; ++j) {
        if (base + j < NDR) rowptr[base + j] = excl + e;
        e += v[j];
    }
    if (t == 255) bsum[blockIdx.x] = ssc[255];
}

__global__ void scan_bsum(int* __restrict__ bsum) {
    if (threadIdx.x == 0) {
        int acc = 0;
        for (int b = 0; b < NBLK_DR; ++b) { int v = bsum[b]; bsum[b] = acc; acc += v; }
    }
}

__global__ __launch_bounds__(256) void scan_add(int* __restrict__ rowptr,
                                                const int* __restrict__ bsum) {
    int i = blockIdx.x * blockDim.x + threadIdx.x;
    if (i < NDR) rowptr[i] += bsum[i >> 10];
    if (i == 0) rowptr[NDR] = NE;
}

// ---------------- fill CSR: epk[slot] = src
__global__ void fill_kernel(const int* __restrict__ ei, const int* __restrict__ ea,
                            const int* __restrict__ rowptr, int* __restrict__ fillc,
                            int* __restrict__ epk) {
    int e = blockIdx.x * blockDim.x + threadIdx.x;
    if (e >= NE) return;
    int src = ei[e];
    int dst = ei[NE + e];
    int bucket = ea[e] * NN + dst;
    int pos = atomicAdd(&fillc[bucket], 1);
    epk[rowptr[bucket] + pos] = src;
}

// ---------------- fused RGCN layer: hout = relu([hin | mean_r(hin)] @ Wcat + bias)
// block = 64 dst rows; K-chunks: c=0 copy of hin, c=1+r gather-mean of relation r from hin.
__global__ __launch_bounds__(256) void rgcn_layer(const unsigned short* __restrict__ hin,
                                                  const int* __restrict__ rowptr_r,
                                                  const int* __restrict__ epk,
                                                  const unsigned short* __restrict__ wT2,
                                                  const float* __restrict__ bias,
                                                  unsigned short* __restrict__ hout) {
    __shared__ __align__(16) unsigned short As[64][136];    // 64 rows x 128 k (+8 pad)
    __shared__ __align__(16) unsigned short Bs[128][136];   // 128 n x 128 k (+8 pad)
    int tid = threadIdx.x;
    int wave = tid >> 6, lane = tid & 63;
    int wm = (wave & 1) * 32, wn = (wave >> 1) * 64;
    int quad = lane >> 4, l16 = lane & 15;
    int row0 = blockIdx.x * 64;

    f32x4 acc[2][4];
#pragma unroll
    for (int i = 0; i < 2; ++i)
#pragma unroll
        for (int j = 0; j < 4; ++j) acc[i][j] = (f32x4){0.f, 0.f, 0.f, 0.f};

    for (int c = 0; c < RELS + 1; ++c) {
        if (c) __syncthreads();   // previous chunk's MFMA reads done

        // stage Bs: 128 n x 128 k slice of wT2
        {
            int n = tid >> 2;
            int c0 = (tid & 3) * 32;
            const uint4* gb0 = (const uint4*)(wT2 + (size_t)n * KTOT + c * HID + c0);
            const uint4* gb1 = (const uint4*)(wT2 + (size_t)(n + 64) * KTOT + c * HID + c0);
#pragma unroll
            for (int q = 0; q < 4; ++q) {
                *(uint4*)&Bs[n][c0 + q * 8] = gb0[q];
                *(uint4*)&Bs[n + 64][c0 + q * 8] = gb1[q];
            }
        }

        // stage As
        if (c == 0) {
            int rr = tid >> 2;
            int c0 = (tid & 3) * 32;
            int grow = row0 + rr;
            const uint4* ga = (const uint4*)(hin + (size_t)grow * HID + c0);
            uint4 z = {0u, 0u, 0u, 0u};
#pragma unroll
            for (int q = 0; q < 4; ++q)
                *(uint4*)&As[rr][c0 + q * 8] = (grow < NN) ? ga[q] : z;
        } else {
            int r = c - 1;
            int rbase = r * NN;
            int wrow0 = row0 + wave * 16;
            int bnd = 0;
            if (lane < 17) {
                int rr2 = wrow0 + lane;
                if (rr2 > NN) rr2 = NN;
                bnd = rowptr_r[rbase + rr2];
            }
            int B0 = __shfl(bnd, 0);
            int B1 = __shfl(bnd, 16);
            int wbase = B0;
            int myp = (wbase + lane < B1) ? epk[wbase + lane] : 0;
            for (int i = 0; i < 16; ++i) {
                int beg = __shfl(bnd, i), end = __shfl(bnd, i + 1);
                float ax = 0.f, ay = 0.f;
                for (int e = beg; e < end; ++e) {
                    if (e - wbase >= 64) {
                        wbase += 64;
                        myp = (wbase + lane < B1) ? epk[wbase + lane] : 0;
                    }
                    int src = __shfl(myp, e - wbase);
                    ushort2 u = *(const ushort2*)(hin + (size_t)src * HID + (lane << 1));
                    ax += bf2f(u.x);
                    ay += bf2f(u.y);
                }
                float s = (end > beg) ? 1.f / (float)(end - beg) : 0.f;
                ushort2 o;
                o.x = f2bf(ax * s);
                o.y = f2bf(ay * s);
                *(ushort2*)&As[wave * 16 + i][lane << 1] = o;
            }
        }
        __syncthreads();

        // MFMA: 4 k-steps over this 128-k chunk
#pragma unroll
        for (int ks = 0; ks < 4; ++ks) {
            int ko = ks * 32 + quad * 8;
            short8 a[2], b[4];
            a[0] = *(const short8*)&As[wm + l16][ko];
            a[1] = *(const short8*)&As[wm + 16 + l16][ko];
#pragma unroll
            for (int j = 0; j < 4; ++j)
                b[j] = *(const short8*)&Bs[wn + j * 16 + l16][ko];
#pragma unroll
            for (int i = 0; i < 2; ++i)
#pragma unroll
                for (int j = 0; j < 4; ++j)
                    acc[i][j] = __builtin_amdgcn_mfma_f32_16x16x32_bf16(a[i], b[j], acc[i][j], 0, 0, 0);
        }
    }

    // epilogue: bias + relu -> bf16 (C/D: col=lane&15, row=quad*4+reg)
#pragma unroll
    for (int i = 0; i < 2; ++i)
#pragma unroll
        for (int reg = 0; reg < 4; ++reg) {
            int grow = row0 + wm + i * 16 + quad * 4 + reg;
            if (grow >= NN) continue;
#pragma unroll
            for (int j = 0; j < 4; ++j) {
                int col = wn + j * 16 + l16;
                float v = acc[i][j][reg] + bias[col];
                hout[(size_t)grow * HID + col] = f2bf(fmaxf(v, 0.f));
            }
        }
}

// ---------------- global mean pool: sorted-batch register accumulation, flush on g-change
__global__ __launch_bounds__(256) void pool_kernel(const unsigned short* __restrict__ habf,
                                                   const int* __restrict__ batch,
                                                   float* __restrict__ psum,
                                                   float* __restrict__ pcnt) {
    int tid = threadIdx.x;
    int f = tid & 127;
    int sub = tid >> 7;
    int base = blockIdx.x * PCHUNK;
    float acc = 0.f, cnt = 0.f;
    int gcur = -1;
    for (int it = 0; it < PCHUNK / 2; ++it) {
        int node = base + it * 2 + sub;
        if (node >= NN) break;
        int g = batch[node];
        if (g != gcur) {
            if (gcur >= 0) {
                atomicAdd(&psum[gcur * HID + f], acc);
                if (f == 0) atomicAdd(&pcnt[gcur], cnt);
            }
            gcur = g; acc = 0.f; cnt = 0.f;
        }
        acc += bf2f(habf[(size_t)node * HID + f]);
        cnt += 1.f;
    }
    if (gcur >= 0) {
        atomicAdd(&psum[gcur * HID + f], acc);
        if (f == 0) atomicAdd(&pcnt[gcur], cnt);
    }
}

// ---------------- head
__global__ void head_kernel(const float* __restrict__ psum, const float* __restrict__ pcnt,
                            const float* __restrict__ g2, const float* __restrict__ b2,
                            const float* __restrict__ m2, const float* __restrict__ v2,
                            const float* __restrict__ fc1w, const float* __restrict__ fc1b,
                            const float* __restrict__ fc2w, const float* __restrict__ fc2b,
                            float* __restrict__ out) {
    __shared__ float v[HID];
    __shared__ float u[HID];
    __shared__ float lg[CLASSES];
    int j = threadIdx.x;
    float acc = 0.f;
    for (int g = 0; g < GRAPHS; ++g) {
        float val = psum[g * HID + j] / fmaxf(pcnt[g], 1.0f);
        val = (val - m2[j]) * rsqrtf(v2[j] + EPSV) * g2[j] + b2[j];
        acc += val;
    }
    v[j] = fmaxf(acc / (float)GRAPHS, 0.f);
    __syncthreads();
    float s = fc1b[j];
    for (int k = 0; k < HID; ++k) s += v[k] * fc1w[k * HID + j];
    u[j] = fmaxf(s, 0.f);
    __syncthreads();
    if (j < CLASSES) {
        float t = fc2b[j];
        for (int k = 0; k < HID; ++k) t += u[k] * fc2w[k * CLASSES + j];
        lg[j] = t;
    }
    __syncthreads();
    if (j < CLASSES) {
        float mx = lg[0];
        for (int c = 1; c < CLASSES; ++c) mx = fmaxf(mx, lg[c]);
        float se = 0.f;
        for (int c = 0; c < CLASSES; ++c) se += expf(lg[c] - mx);
        out[j] = lg[j] - mx - logf(se);
    }
}

extern "C" void kernel_launch(void* const* d_in, const int* in_sizes, int n_in,
                              void* d_out, int out_size, void* d_ws, size_t ws_size,
                              hipStream_t stream) {
    const float* x     = (const float*)d_in[0];
    const int*   ei    = (const int*)d_in[1];
    const int*   ea    = (const int*)d_in[2];
    const int*   batch = (const int*)d_in[3];
    const float* bn1g  = (const float*)d_in[4];
    const float* bn1b  = (const float*)d_in[5];
    const float* bn1m  = (const float*)d_in[6];
    const float* bn1v  = (const float*)d_in[7];
    const float* basis = (const float*)d_in[8];
    const float* comp  = (const float*)d_in[9];
    const float* root  = (const float*)d_in[10];
    const float* bias  = (const float*)d_in[11];
    const float* bn2g  = (const float*)d_in[12];
    const float* bn2b  = (const float*)d_in[13];
    const float* bn2m  = (const float*)d_in[14];
    const float* bn2v  = (const float*)d_in[15];
    const float* fc1w  = (const float*)d_in[16];
    const float* fc1b  = (const float*)d_in[17];
    const float* fc2w  = (const float*)d_in[18];
    const float* fc2b  = (const float*)d_in[19];

    float* ws = (float*)d_ws;
    size_t off = 0;
    unsigned short* wT2 = (unsigned short*)(ws + off); off += (size_t)LAYERS * HID * KTOT / 2;
    unsigned short* habf0 = (unsigned short*)(ws + off); off += (size_t)NN * HID / 2;
    unsigned short* habf1 = (unsigned short*)(ws + off); off += (size_t)NN * HID / 2;
    float* psum   = ws + off; off += (size_t)GRAPHS * HID + GRAPHS;
    float* pcnt   = psum + GRAPHS * HID;
    int* cntb     = (int*)(ws + off); off += (size_t)NDR;      // cntb+fillc adjacent: one memset
    int* fillc    = (int*)(ws + off); off += (size_t)NDR;
    int* rowptr_r = (int*)(ws + off); off += (size_t)NDR + 1;
    int* bsum     = (int*)(ws + off); off += (size_t)NBLK_DR;
    int* epk      = (int*)(ws + off); off += (size_t)NE;
    if (ws_size < off * sizeof(float)) return;

    hipMemsetAsync(psum, 0, (GRAPHS * HID + GRAPHS) * sizeof(float), stream);
    hipMemsetAsync(cntb, 0, (size_t)2 * NDR * sizeof(int), stream);

    build_wcat<<<(LAYERS * HID * KTOT + 255) / 256, 256, 0, stream>>>(basis, comp, root, wT2);
    bn1_kernel<<<(NN * HID + 255) / 256, 256, 0, stream>>>(x, bn1g, bn1b, bn1m, bn1v, habf0);

    // relation-major CSR build (once per call)
    deg_kernel<<<(NE + 255) / 256, 256, 0, stream>>>(ei, ea, cntb);
    scan_partial<<<NBLK_DR, 256, 0, stream>>>(cntb, rowptr_r, bsum);
    scan_bsum<<<1, 64, 0, stream>>>(bsum);
    scan_add<<<(NDR + 255) / 256, 256, 0, stream>>>(rowptr_r, bsum);
    fill_kernel<<<(NE + 255) / 256, 256, 0, stream>>>(ei, ea, rowptr_r, fillc, epk);

    unsigned short* hin = habf0;
    unsigned short* hout = habf1;
    for (int l = 0; l < LAYERS; ++l) {
        rgcn_layer<<<(NN + 63) / 64, 256, 0, stream>>>(hin, rowptr_r, epk,
                                                       wT2 + (size_t)l * HID * KTOT,
                                                       bias + (size_t)l * HID, hout);
        unsigned short* t = hin; hin = hout; hout = t;
    }

    pool_kernel<<<(NN + PCHUNK - 1) / PCHUNK, 256, 0, stream>>>(hin, batch, psum, pcnt);
    head_kernel<<<1, 128, 0, stream>>>(psum, pcnt, bn2g, bn2b, bn2m, bn2v,
                                       fc1w, fc1b, fc2w, fc2b, (float*)d_out);
}

// Round 8
// 490.158 us; speedup vs baseline: 1.7376x; 1.7376x over previous
//
#include <hip/hip_runtime.h>
#include <hip/hip_bf16.h>

#define NN 50000
#define NE 500000
#define HID 128
#define LAYERS 3
#define RELS 8
#define BASES 30
#define GRAPHS 16
#define CLASSES 8
#define EPSV 1e-5f
#define NOUT (HID * (RELS + 1))   // 1152
#define SCAN_CHUNK 1024
#define SCAN_NBLK ((NN + SCAN_CHUNK - 1) / SCAN_CHUNK)   // 49
#define PCHUNK 128

typedef __attribute__((ext_vector_type(8))) short short8;   // 8 bf16 (4 VGPRs)
typedef __attribute__((ext_vector_type(4))) float f32x4;    // MFMA accumulator
typedef __attribute__((ext_vector_type(2))) float f32x2;

__device__ __forceinline__ float bf2f(unsigned short u) {
    union { unsigned int i; float f; } x; x.i = ((unsigned int)u) << 16; return x.f;
}
__device__ __forceinline__ unsigned short f2bf(float f) {
    __hip_bfloat16 b = __float2bfloat16(f);
    return *(unsigned short*)&b;
}
// HW fp8 (OCP e4m3 on gfx950) pack/unpack
__device__ __forceinline__ unsigned char f2fp8(float a) {
    return (unsigned char)(__builtin_amdgcn_cvt_pk_fp8_f32(a, a, 0, false) & 0xFF);
}
__device__ __forceinline__ f32x2 fp8x2_2f(unsigned short u) {
    return __builtin_amdgcn_cvt_pk_f32_fp8((int)u, false);
}

// ---------------- wT: [L][1152 n][128 k] bf16
__global__ void build_wcat(const float* __restrict__ basis, const float* __restrict__ comp,
                           const float* __restrict__ root, unsigned short* __restrict__ wT) {
    int idx = blockIdx.x * blockDim.x + threadIdx.x;
    if (idx >= LAYERS * NOUT * HID) return;
    int k = idx & (HID - 1);
    int rest = idx >> 7;
    int n = rest % NOUT;
    int l = rest / NOUT;
    float v;
    if (n < HID) {
        v = root[((size_t)l * HID + k) * HID + n];
    } else {
        int r = (n >> 7) - 1;
        int j = n & (HID - 1);
        const float* cp = comp + ((size_t)l * RELS + r) * BASES;
        float s = 0.f;
        for (int b = 0; b < BASES; ++b)
            s += cp[b] * basis[(((size_t)(l * BASES + b)) * HID + k) * HID + j];
        v = s;
    }
    wT[idx] = f2bf(v);
}

// ---------------- BN1 (eval mode) -> bf16
__global__ void bn1_kernel(const float* __restrict__ x, const float* __restrict__ gamma,
                           const float* __restrict__ beta, const float* __restrict__ mean,
                           const float* __restrict__ var, unsigned short* __restrict__ habf) {
    int idx = blockIdx.x * blockDim.x + threadIdx.x;
    if (idx >= NN * HID) return;
    int f = idx & (HID - 1);
    habf[idx] = f2bf((x[idx] - mean[f]) * rsqrtf(var[f] + EPSV) * gamma[f] + beta[f]);
}

// ---------------- degree count per (dst, rel)
__global__ void deg_kernel(const int* __restrict__ ei, const int* __restrict__ ea,
                           float* __restrict__ deg) {
    int e = blockIdx.x * blockDim.x + threadIdx.x;
    if (e >= NE) return;
    int dst = ei[NE + e];
    atomicAdd(&deg[(size_t)dst * RELS + ea[e]], 1.0f);
}

// degi = int total degree; deg -> invdeg in-place
__global__ void invdeg_kernel(float* __restrict__ deg, int* __restrict__ degi) {
    int n = blockIdx.x * blockDim.x + threadIdx.x;
    if (n >= NN) return;
    float s = 0.f;
#pragma unroll
    for (int r = 0; r < RELS; ++r) {
        float d = deg[(size_t)n * RELS + r];
        s += d;
        deg[(size_t)n * RELS + r] = 1.0f / fmaxf(d, 1.0f);
    }
    degi[n] = (int)(s + 0.5f);
}

// ---------------- exclusive scan of degi -> rowptr
__global__ __launch_bounds__(256) void scan_partial(const int* __restrict__ degi,
                                                    int* __restrict__ rowptr,
                                                    int* __restrict__ bsum) {
    __shared__ int ssc[256];
    int t = threadIdx.x;
    int base = blockIdx.x * SCAN_CHUNK + t * 4;
    int v[4];
#pragma unroll
    for (int j = 0; j < 4; ++j) v[j] = (base + j < NN) ? degi[base + j] : 0;
    int tsum = v[0] + v[1] + v[2] + v[3];
    ssc[t] = tsum;
    __syncthreads();
    for (int ofs = 1; ofs < 256; ofs <<= 1) {
        int add = (t >= ofs) ? ssc[t - ofs] : 0;
        __syncthreads();
        ssc[t] += add;
        __syncthreads();
    }
    int excl = ssc[t] - tsum;
    int e = 0;
#pragma unroll
    for (int j = 0; j < 4; ++j) {
        if (base + j < NN) rowptr[base + j] = excl + e;
        e += v[j];
    }
    if (t == 255) bsum[blockIdx.x] = ssc[255];
}

__global__ void scan_bsum(int* __restrict__ bsum) {
    if (threadIdx.x == 0) {
        int acc = 0;
        for (int b = 0; b < SCAN_NBLK; ++b) { int v = bsum[b]; bsum[b] = acc; acc += v; }
    }
}

__global__ __launch_bounds__(256) void scan_add(int* __restrict__ rowptr,
                                                const int* __restrict__ bsum) {
    int i = blockIdx.x * blockDim.x + threadIdx.x;
    if (i < NN) rowptr[i] += bsum[i >> 10];
    if (i == 0) rowptr[NN] = NE;
}

// ---------------- fill CSR
__global__ void fill_kernel(const int* __restrict__ ei, const int* __restrict__ ea,
                            const int* __restrict__ rowptr, const float* __restrict__ invdeg,
                            int* __restrict__ fillcnt, int* __restrict__ epk,
                            float* __restrict__ escale) {
    int e = blockIdx.x * blockDim.x + threadIdx.x;
    if (e >= NE) return;
    int src = ei[e];
    int dst = ei[NE + e];
    int r = ea[e];
    int pos = atomicAdd(&fillcnt[dst], 1);
    int slot = rowptr[dst] + pos;
    epk[slot] = src | (r << 20);
    escale[slot] = invdeg[(size_t)dst * RELS + r];
}

// ---------------- MFMA GEMM, single-pass: one block = 64-row stripe, loops all 9 n-tiles.
// A staged once (64x128), B staged per (n-tile, k-half). tile0 -> hnb bf16(+bias); 1..8 -> xwb fp8.
__global__ __launch_bounds__(256) void gemm_mfma(const unsigned short* __restrict__ habf,
                                                 const unsigned short* __restrict__ wT,
                                                 const float* __restrict__ bias,
                                                 unsigned short* __restrict__ hnb,
                                                 unsigned char* __restrict__ xwb) {
    __shared__ __align__(16) unsigned short As[64][136];   // 64 rows x 128 k (+8 pad)
    __shared__ __align__(16) unsigned short Bs[128][72];   // 128 n x 64 k (+8 pad)
    int tid = threadIdx.x;
    int wave = tid >> 6, lane = tid & 63;
    int wm = (wave & 1) * 32, wn = (wave >> 1) * 64;
    int quad = lane >> 4, l16 = lane & 15;
    int row0 = blockIdx.x * 64;

    // stage A once: 4 threads/row, each 4 uint4 (32 bf16)
    {
        int r = tid >> 2;
        int c0 = (tid & 3) * 32;
        int grow = row0 + r;
        const uint4* ga = (const uint4*)(habf + (size_t)grow * HID + c0);
        uint4 z = {0u, 0u, 0u, 0u};
#pragma unroll
        for (int c = 0; c < 4; ++c)
            *(uint4*)&As[r][c0 + c * 8] = (grow < NN) ? ga[c] : z;
    }

    for (int n0 = 0; n0 < RELS + 1; ++n0) {
        f32x4 acc[2][4];
#pragma unroll
        for (int i = 0; i < 2; ++i)
#pragma unroll
            for (int j = 0; j < 4; ++j) acc[i][j] = (f32x4){0.f, 0.f, 0.f, 0.f};

#pragma unroll
        for (int kh = 0; kh < 2; ++kh) {
            __syncthreads();   // Bs consumed (or A staged on first pass)
            {
                int r = tid >> 1;
                int c0 = (tid & 1) * 32;
                const uint4* gb = (const uint4*)(wT + (size_t)(n0 * 128 + r) * HID + kh * 64 + c0);
#pragma unroll
                for (int c = 0; c < 4; ++c)
                    *(uint4*)&Bs[r][c0 + c * 8] = gb[c];
            }
            __syncthreads();
#pragma unroll
            for (int kc = 0; kc < 2; ++kc) {
                int ko = kc * 32 + quad * 8;
                short8 a[2], b[4];
                a[0] = *(const short8*)&As[wm + l16][kh * 64 + ko];
                a[1] = *(const short8*)&As[wm + 16 + l16][kh * 64 + ko];
#pragma unroll
                for (int j = 0; j < 4; ++j)
                    b[j] = *(const short8*)&Bs[wn + j * 16 + l16][ko];
#pragma unroll
                for (int i = 0; i < 2; ++i)
#pragma unroll
                    for (int j = 0; j < 4; ++j)
                        acc[i][j] = __builtin_amdgcn_mfma_f32_16x16x32_bf16(a[i], b[j], acc[i][j], 0, 0, 0);
            }
        }

        // epilogue for this n-tile (C/D: col=lane&15, row=quad*4+reg)
        if (n0 == 0) {
#pragma unroll
            for (int i = 0; i < 2; ++i)
#pragma unroll
                for (int reg = 0; reg < 4; ++reg) {
                    int grow = row0 + wm + i * 16 + quad * 4 + reg;
                    if (grow >= NN) continue;
#pragma unroll
                    for (int j = 0; j < 4; ++j) {
                        int col = wn + j * 16 + l16;
                        hnb[(size_t)grow * HID + col] = f2bf(acc[i][j][reg] + bias[col]);
                    }
                }
        } else {
            int cbase = (n0 - 1) * 128;
#pragma unroll
            for (int i = 0; i < 2; ++i)
#pragma unroll
                for (int reg = 0; reg < 4; ++reg) {
                    int grow = row0 + wm + i * 16 + quad * 4 + reg;
                    if (grow >= NN) continue;
#pragma unroll
                    for (int j = 0; j < 4; ++j) {
                        int col = wn + j * 16 + l16;
                        xwb[(size_t)grow * (RELS * HID) + cbase + col] = f2fp8(acc[i][j][reg]);
                    }
                }
        }
    }
}

// ---------------- aggregate (atomic-free): one wave per dst node, edge prefetch + shfl
// habf[dst] = bf16(relu(hnb[dst] + sum_edges fp8(xwb[src][r]) * escale))
__global__ __launch_bounds__(256) void aggregate_kernel(const int* __restrict__ rowptr,
                                                        const int* __restrict__ epk,
                                                        const float* __restrict__ escale,
                                                        const unsigned char* __restrict__ xwb,
                                                        const unsigned short* __restrict__ hnb,
                                                        unsigned short* __restrict__ habf) {
    int node = (blockIdx.x << 2) + (threadIdx.x >> 6);
    if (node >= NN) return;
    int lane = threadIdx.x & 63;
    int beg = rowptr[node], end = rowptr[node + 1];
    float ax = 0.f, ay = 0.f;
    for (int b0 = beg; b0 < end; b0 += 64) {
        int cnt = min(64, end - b0);
        int myp = 0; float mys = 0.f;
        if (lane < cnt) { myp = epk[b0 + lane]; mys = escale[b0 + lane]; }
        int j = 0;
        for (; j + 4 <= cnt; j += 4) {
            int p0 = __shfl(myp, j),     p1 = __shfl(myp, j + 1);
            int p2 = __shfl(myp, j + 2), p3 = __shfl(myp, j + 3);
            float s0 = __shfl(mys, j),     s1 = __shfl(mys, j + 1);
            float s2 = __shfl(mys, j + 2), s3 = __shfl(mys, j + 3);
            unsigned short u0 = *(const unsigned short*)(xwb + (size_t)(p0 & 0xFFFFF) * (RELS * HID) + (p0 >> 20) * HID + lane * 2);
            unsigned short u1 = *(const unsigned short*)(xwb + (size_t)(p1 & 0xFFFFF) * (RELS * HID) + (p1 >> 20) * HID + lane * 2);
            unsigned short u2 = *(const unsigned short*)(xwb + (size_t)(p2 & 0xFFFFF) * (RELS * HID) + (p2 >> 20) * HID + lane * 2);
            unsigned short u3 = *(const unsigned short*)(xwb + (size_t)(p3 & 0xFFFFF) * (RELS * HID) + (p3 >> 20) * HID + lane * 2);
            f32x2 v0 = fp8x2_2f(u0), v1 = fp8x2_2f(u1), v2 = fp8x2_2f(u2), v3 = fp8x2_2f(u3);
            ax += v0.x * s0 + v1.x * s1 + v2.x * s2 + v3.x * s3;
            ay += v0.y * s0 + v1.y * s1 + v2.y * s2 + v3.y * s3;
        }
        for (; j < cnt; ++j) {
            int p = __shfl(myp, j);
            float s = __shfl(mys, j);
            unsigned short u = *(const unsigned short*)(xwb + (size_t)(p & 0xFFFFF) * (RELS * HID) + (p >> 20) * HID + lane * 2);
            f32x2 v = fp8x2_2f(u);
            ax += v.x * s;
            ay += v.y * s;
        }
    }
    ushort2 cu = *((const ushort2*)(hnb + (size_t)node * HID) + lane);
    ushort2 o;
    o.x = f2bf(fmaxf(bf2f(cu.x) + ax, 0.f));
    o.y = f2bf(fmaxf(bf2f(cu.y) + ay, 0.f));
    *((ushort2*)(habf + (size_t)node * HID) + lane) = o;
}

// ---------------- global mean pool: sorted-batch register accumulation, flush on g-change
__global__ __launch_bounds__(256) void pool_kernel(const unsigned short* __restrict__ habf,
                                                   const int* __restrict__ batch,
                                                   float* __restrict__ psum,
                                                   float* __restrict__ pcnt) {
    int tid = threadIdx.x;
    int f = tid & 127;
    int sub = tid >> 7;
    int base = blockIdx.x * PCHUNK;
    float acc = 0.f, cnt = 0.f;
    int gcur = -1;
    for (int it = 0; it < PCHUNK / 2; ++it) {
        int node = base + it * 2 + sub;
        if (node >= NN) break;
        int g = batch[node];
        if (g != gcur) {
            if (gcur >= 0) {
                atomicAdd(&psum[gcur * HID + f], acc);
                if (f == 0) atomicAdd(&pcnt[gcur], cnt);
            }
            gcur = g; acc = 0.f; cnt = 0.f;
        }
        acc += bf2f(habf[(size_t)node * HID + f]);
        cnt += 1.f;
    }
    if (gcur >= 0) {
        atomicAdd(&psum[gcur * HID + f], acc);
        if (f == 0) atomicAdd(&pcnt[gcur], cnt);
    }
}

// ---------------- head
__global__ void head_kernel(const float* __restrict__ psum, const float* __restrict__ pcnt,
                            const float* __restrict__ g2, const float* __restrict__ b2,
                            const float* __restrict__ m2, const float* __restrict__ v2,
                            const float* __restrict__ fc1w, const float* __restrict__ fc1b,
                            const float* __restrict__ fc2w, const float* __restrict__ fc2b,
                            float* __restrict__ out) {
    __shared__ float v[HID];
    __shared__ float u[HID];
    __shared__ float lg[CLASSES];
    int j = threadIdx.x;
    float acc = 0.f;
    for (int g = 0; g < GRAPHS; ++g) {
        float val = psum[g * HID + j] / fmaxf(pcnt[g], 1.0f);
        val = (val - m2[j]) * rsqrtf(v2[j] + EPSV) * g2[j] + b2[j];
        acc += val;
    }
    v[j] = fmaxf(acc / (float)GRAPHS, 0.f);
    __syncthreads();
    float s = fc1b[j];
    for (int k = 0; k < HID; ++k) s += v[k] * fc1w[k * HID + j];
    u[j] = fmaxf(s, 0.f);
    __syncthreads();
    if (j < CLASSES) {
        float t = fc2b[j];
        for (int k = 0; k < HID; ++k) t += u[k] * fc2w[k * CLASSES + j];
        lg[j] = t;
    }
    __syncthreads();
    if (j < CLASSES) {
        float mx = lg[0];
        for (int c = 1; c < CLASSES; ++c) mx = fmaxf(mx, lg[c]);
        float se = 0.f;
        for (int c = 0; c < CLASSES; ++c) se += expf(lg[c] - mx);
        out[j] = lg[j] - mx - logf(se);
    }
}

extern "C" void kernel_launch(void* const* d_in, const int* in_sizes, int n_in,
                              void* d_out, int out_size, void* d_ws, size_t ws_size,
                              hipStream_t stream) {
    const float* x     = (const float*)d_in[0];
    const int*   ei    = (const int*)d_in[1];
    const int*   ea    = (const int*)d_in[2];
    const int*   batch = (const int*)d_in[3];
    const float* bn1g  = (const float*)d_in[4];
    const float* bn1b  = (const float*)d_in[5];
    const float* bn1m  = (const float*)d_in[6];
    const float* bn1v  = (const float*)d_in[7];
    const float* basis = (const float*)d_in[8];
    const float* comp  = (const float*)d_in[9];
    const float* root  = (const float*)d_in[10];
    const float* bias  = (const float*)d_in[11];
    const float* bn2g  = (const float*)d_in[12];
    const float* bn2b  = (const float*)d_in[13];
    const float* bn2m  = (const float*)d_in[14];
    const float* bn2v  = (const float*)d_in[15];
    const float* fc1w  = (const float*)d_in[16];
    const float* fc1b  = (const float*)d_in[17];
    const float* fc2w  = (const float*)d_in[18];
    const float* fc2b  = (const float*)d_in[19];

    float* ws = (float*)d_ws;
    size_t off = 0;
    unsigned short* wT = (unsigned short*)(ws + off); off += (size_t)LAYERS * NOUT * HID / 2;
    unsigned short* hnb  = (unsigned short*)(ws + off); off += (size_t)NN * HID / 2;
    unsigned short* habf = (unsigned short*)(ws + off); off += (size_t)NN * HID / 2;
    float* deg    = ws + off; off += (size_t)NN * RELS;
    float* psum   = ws + off; off += (size_t)GRAPHS * HID + GRAPHS;
    float* pcnt   = psum + GRAPHS * HID;
    float* escale = ws + off; off += (size_t)NE;
    int* degi     = (int*)(ws + off); off += (size_t)NN;
    int* rowptr   = (int*)(ws + off); off += (size_t)NN + 1;
    int* fillcnt  = (int*)(ws + off); off += (size_t)NN;
    int* bsum     = (int*)(ws + off); off += (size_t)SCAN_NBLK;
    int* epk      = (int*)(ws + off); off += (size_t)NE;
    off = (off + 3) & ~(size_t)3;
    unsigned char* xwb = (unsigned char*)(ws + off);
    off += (size_t)NN * RELS * HID / 4;                 // fp8: 51.2 MB
    if (ws_size < off * sizeof(float)) return;

    hipMemsetAsync(psum, 0, (GRAPHS * HID + GRAPHS) * sizeof(float), stream);
    hipMemsetAsync(deg, 0, (size_t)NN * RELS * sizeof(float), stream);
    hipMemsetAsync(fillcnt, 0, (size_t)NN * sizeof(int), stream);

    build_wcat<<<(LAYERS * NOUT * HID + 255) / 256, 256, 0, stream>>>(basis, comp, root, wT);
    bn1_kernel<<<(NN * HID + 255) / 256, 256, 0, stream>>>(x, bn1g, bn1b, bn1m, bn1v, habf);

    deg_kernel<<<(NE + 255) / 256, 256, 0, stream>>>(ei, ea, deg);
    invdeg_kernel<<<(NN + 255) / 256, 256, 0, stream>>>(deg, degi);
    scan_partial<<<SCAN_NBLK, 256, 0, stream>>>(degi, rowptr, bsum);
    scan_bsum<<<1, 64, 0, stream>>>(bsum);
    scan_add<<<(NN + 255) / 256, 256, 0, stream>>>(rowptr, bsum);
    fill_kernel<<<(NE + 255) / 256, 256, 0, stream>>>(ei, ea, rowptr, deg, fillcnt, epk, escale);

    for (int l = 0; l < LAYERS; ++l) {
        gemm_mfma<<<(NN + 63) / 64, 256, 0, stream>>>(habf, wT + (size_t)l * NOUT * HID,
                                                      bias + (size_t)l * HID, hnb, xwb);
        aggregate_kernel<<<(NN + 3) / 4, 256, 0, stream>>>(rowptr, epk, escale, xwb, hnb, habf);
    }

    pool_kernel<<<(NN + PCHUNK - 1) / PCHUNK, 256, 0, stream>>>(habf, batch, psum, pcnt);
    head_kernel<<<1, 128, 0, stream>>>(psum, pcnt, bn2g, bn2b, bn2m, bn2v,
                                       fc1w, fc1b, fc2w, fc2b, (float*)d_out);
}

// Round 9
// 451.174 us; speedup vs baseline: 1.8878x; 1.0864x over previous
//
#include <hip/hip_runtime.h>
#include <hip/hip_bf16.h>

#define NN 50000
#define NE 500000
#define HID 128
#define LAYERS 3
#define RELS 8
#define BASES 30
#define GRAPHS 16
#define CLASSES 8
#define EPSV 1e-5f
#define NOUT (HID * (RELS + 1))   // 1152
#define SCAN_CHUNK 1024
#define SCAN_NBLK ((NN + SCAN_CHUNK - 1) / SCAN_CHUNK)   // 49
#define PCHUNK 128

typedef __attribute__((ext_vector_type(8))) short short8;   // 8 bf16 (4 VGPRs)
typedef __attribute__((ext_vector_type(4))) float f32x4;    // MFMA accumulator
typedef __attribute__((ext_vector_type(2))) float f32x2;

__device__ __forceinline__ float bf2f(unsigned short u) {
    union { unsigned int i; float f; } x; x.i = ((unsigned int)u) << 16; return x.f;
}
__device__ __forceinline__ unsigned short f2bf(float f) {
    __hip_bfloat16 b = __float2bfloat16(f);
    return *(unsigned short*)&b;
}
// HW fp8 (OCP e4m3 on gfx950) pack/unpack
__device__ __forceinline__ unsigned char f2fp8(float a) {
    return (unsigned char)(__builtin_amdgcn_cvt_pk_fp8_f32(a, a, 0, false) & 0xFF);
}
__device__ __forceinline__ f32x2 fp8x2_2f(unsigned short u) {
    return __builtin_amdgcn_cvt_pk_f32_fp8((int)u, false);
}

// ---------------- wT: [L][1152 n][128 k] bf16
// block = (l, k-pair); lanes span j (coalesced basis reads); all 8 relations per load.
__global__ __launch_bounds__(256) void build_wcat(const float* __restrict__ basis,
                                                  const float* __restrict__ comp,
                                                  const float* __restrict__ root,
                                                  unsigned short* __restrict__ wT) {
    int bid = blockIdx.x;
    int l = bid >> 6;               // 0..2
    int k0 = (bid & 63) << 1;       // 0,2,..,126
    __shared__ float cl[RELS * BASES];   // 240
    int tid = threadIdx.x;
    if (tid < RELS * BASES) cl[tid] = comp[l * RELS * BASES + tid];
    __syncthreads();
    int j = tid & 127;
    int k = k0 + (tid >> 7);
    const float* bp = basis + ((size_t)l * BASES * HID + k) * HID + j;
    float acc[RELS];
#pragma unroll
    for (int r = 0; r < RELS; ++r) acc[r] = 0.f;
    for (int b = 0; b < BASES; ++b) {
        float v = bp[(size_t)b * HID * HID];
#pragma unroll
        for (int r = 0; r < RELS; ++r) acc[r] += cl[r * BASES + b] * v;
    }
    unsigned short* wl = wT + (size_t)l * NOUT * HID;
#pragma unroll
    for (int r = 0; r < RELS; ++r)
        wl[(size_t)((1 + r) * HID + j) * HID + k] = f2bf(acc[r]);
    // root columns: wT[l][j][k] = root[l][k][j]
    wl[(size_t)j * HID + k] = f2bf(root[((size_t)l * HID + k) * HID + j]);
}

// ---------------- BN1 (eval mode) -> bf16
__global__ void bn1_kernel(const float* __restrict__ x, const float* __restrict__ gamma,
                           const float* __restrict__ beta, const float* __restrict__ mean,
                           const float* __restrict__ var, unsigned short* __restrict__ habf) {
    int idx = blockIdx.x * blockDim.x + threadIdx.x;
    if (idx >= NN * HID) return;
    int f = idx & (HID - 1);
    habf[idx] = f2bf((x[idx] - mean[f]) * rsqrtf(var[f] + EPSV) * gamma[f] + beta[f]);
}

// ---------------- degree count per (dst, rel)
__global__ void deg_kernel(const int* __restrict__ ei, const int* __restrict__ ea,
                           float* __restrict__ deg) {
    int e = blockIdx.x * blockDim.x + threadIdx.x;
    if (e >= NE) return;
    int dst = ei[NE + e];
    atomicAdd(&deg[(size_t)dst * RELS + ea[e]], 1.0f);
}

// degi = int total degree; deg -> invdeg in-place
__global__ void invdeg_kernel(float* __restrict__ deg, int* __restrict__ degi) {
    int n = blockIdx.x * blockDim.x + threadIdx.x;
    if (n >= NN) return;
    float s = 0.f;
#pragma unroll
    for (int r = 0; r < RELS; ++r) {
        float d = deg[(size_t)n * RELS + r];
        s += d;
        deg[(size_t)n * RELS + r] = 1.0f / fmaxf(d, 1.0f);
    }
    degi[n] = (int)(s + 0.5f);
}

// ---------------- exclusive scan of degi -> rowptr
__global__ __launch_bounds__(256) void scan_partial(const int* __restrict__ degi,
                                                    int* __restrict__ rowptr,
                                                    int* __restrict__ bsum) {
    __shared__ int ssc[256];
    int t = threadIdx.x;
    int base = blockIdx.x * SCAN_CHUNK + t * 4;
    int v[4];
#pragma unroll
    for (int j = 0; j < 4; ++j) v[j] = (base + j < NN) ? degi[base + j] : 0;
    int tsum = v[0] + v[1] + v[2] + v[3];
    ssc[t] = tsum;
    __syncthreads();
    for (int ofs = 1; ofs < 256; ofs <<= 1) {
        int add = (t >= ofs) ? ssc[t - ofs] : 0;
        __syncthreads();
        ssc[t] += add;
        __syncthreads();
    }
    int excl = ssc[t] - tsum;
    int e = 0;
#pragma unroll
    for (int j = 0; j < 4; ++j) {
        if (base + j < NN) rowptr[base + j] = excl + e;
        e += v[j];
    }
    if (t == 255) bsum[blockIdx.x] = ssc[255];
}

__global__ void scan_bsum(int* __restrict__ bsum) {
    if (threadIdx.x == 0) {
        int acc = 0;
        for (int b = 0; b < SCAN_NBLK; ++b) { int v = bsum[b]; bsum[b] = acc; acc += v; }
    }
}

__global__ __launch_bounds__(256) void scan_add(int* __restrict__ rowptr,
                                                const int* __restrict__ bsum) {
    int i = blockIdx.x * blockDim.x + threadIdx.x;
    if (i < NN) rowptr[i] += bsum[i >> 10];
    if (i == 0) rowptr[NN] = NE;
}

// ---------------- fill CSR
__global__ void fill_kernel(const int* __restrict__ ei, const int* __restrict__ ea,
                            const int* __restrict__ rowptr, const float* __restrict__ invdeg,
                            int* __restrict__ fillcnt, int* __restrict__ epk,
                            float* __restrict__ escale) {
    int e = blockIdx.x * blockDim.x + threadIdx.x;
    if (e >= NE) return;
    int src = ei[e];
    int dst = ei[NE + e];
    int r = ea[e];
    int pos = atomicAdd(&fillcnt[dst], 1);
    int slot = rowptr[dst] + pos;
    epk[slot] = src | (r << 20);
    escale[slot] = invdeg[(size_t)dst * RELS + r];
}

// ---------------- MFMA GEMM, single-pass: one block = 64-row stripe, loops all 9 n-tiles.
// A staged once (64x128), B staged per (n-tile, k-half). tile0 -> hnb bf16(+bias); 1..8 -> xwb fp8.
__global__ __launch_bounds__(256) void gemm_mfma(const unsigned short* __restrict__ habf,
                                                 const unsigned short* __restrict__ wT,
                                                 const float* __restrict__ bias,
                                                 unsigned short* __restrict__ hnb,
                                                 unsigned char* __restrict__ xwb) {
    __shared__ __align__(16) unsigned short As[64][136];   // 64 rows x 128 k (+8 pad)
    __shared__ __align__(16) unsigned short Bs[128][72];   // 128 n x 64 k (+8 pad)
    int tid = threadIdx.x;
    int wave = tid >> 6, lane = tid & 63;
    int wm = (wave & 1) * 32, wn = (wave >> 1) * 64;
    int quad = lane >> 4, l16 = lane & 15;
    int row0 = blockIdx.x * 64;

    // stage A once: 4 threads/row, each 4 uint4 (32 bf16)
    {
        int r = tid >> 2;
        int c0 = (tid & 3) * 32;
        int grow = row0 + r;
        const uint4* ga = (const uint4*)(habf + (size_t)grow * HID + c0);
        uint4 z = {0u, 0u, 0u, 0u};
#pragma unroll
        for (int c = 0; c < 4; ++c)
            *(uint4*)&As[r][c0 + c * 8] = (grow < NN) ? ga[c] : z;
    }

    for (int n0 = 0; n0 < RELS + 1; ++n0) {
        f32x4 acc[2][4];
#pragma unroll
        for (int i = 0; i < 2; ++i)
#pragma unroll
            for (int j = 0; j < 4; ++j) acc[i][j] = (f32x4){0.f, 0.f, 0.f, 0.f};

#pragma unroll
        for (int kh = 0; kh < 2; ++kh) {
            __syncthreads();   // Bs consumed (or A staged on first pass)
            {
                int r = tid >> 1;
                int c0 = (tid & 1) * 32;
                const uint4* gb = (const uint4*)(wT + (size_t)(n0 * 128 + r) * HID + kh * 64 + c0);
#pragma unroll
                for (int c = 0; c < 4; ++c)
                    *(uint4*)&Bs[r][c0 + c * 8] = gb[c];
            }
            __syncthreads();
#pragma unroll
            for (int kc = 0; kc < 2; ++kc) {
                int ko = kc * 32 + quad * 8;
                short8 a[2], b[4];
                a[0] = *(const short8*)&As[wm + l16][kh * 64 + ko];
                a[1] = *(const short8*)&As[wm + 16 + l16][kh * 64 + ko];
#pragma unroll
                for (int j = 0; j < 4; ++j)
                    b[j] = *(const short8*)&Bs[wn + j * 16 + l16][ko];
#pragma unroll
                for (int i = 0; i < 2; ++i)
#pragma unroll
                    for (int j = 0; j < 4; ++j)
                        acc[i][j] = __builtin_amdgcn_mfma_f32_16x16x32_bf16(a[i], b[j], acc[i][j], 0, 0, 0);
            }
        }

        // epilogue for this n-tile (C/D: col=lane&15, row=quad*4+reg)
        if (n0 == 0) {
#pragma unroll
            for (int i = 0; i < 2; ++i)
#pragma unroll
                for (int reg = 0; reg < 4; ++reg) {
                    int grow = row0 + wm + i * 16 + quad * 4 + reg;
                    if (grow >= NN) continue;
#pragma unroll
                    for (int j = 0; j < 4; ++j) {
                        int col = wn + j * 16 + l16;
                        hnb[(size_t)grow * HID + col] = f2bf(acc[i][j][reg] + bias[col]);
                    }
                }
        } else {
            int cbase = (n0 - 1) * 128;
#pragma unroll
            for (int i = 0; i < 2; ++i)
#pragma unroll
                for (int reg = 0; reg < 4; ++reg) {
                    int grow = row0 + wm + i * 16 + quad * 4 + reg;
                    if (grow >= NN) continue;
#pragma unroll
                    for (int j = 0; j < 4; ++j) {
                        int col = wn + j * 16 + l16;
                        xwb[(size_t)grow * (RELS * HID) + cbase + col] = f2fp8(acc[i][j][reg]);
                    }
                }
        }
    }
}

// ---------------- aggregate (atomic-free): one wave per dst node, edge prefetch + shfl
// habf[dst] = bf16(relu(hnb[dst] + sum_edges fp8(xwb[src][r]) * escale))
__global__ __launch_bounds__(256) void aggregate_kernel(const int* __restrict__ rowptr,
                                                        const int* __restrict__ epk,
                                                        const float* __restrict__ escale,
                                                        const unsigned char* __restrict__ xwb,
                                                        const unsigned short* __restrict__ hnb,
                                                        unsigned short* __restrict__ habf) {
    int node = (blockIdx.x << 2) + (threadIdx.x >> 6);
    if (node >= NN) return;
    int lane = threadIdx.x & 63;
    int beg = rowptr[node], end = rowptr[node + 1];
    float ax = 0.f, ay = 0.f;
    for (int b0 = beg; b0 < end; b0 += 64) {
        int cnt = min(64, end - b0);
        int myp = 0; float mys = 0.f;
        if (lane < cnt) { myp = epk[b0 + lane]; mys = escale[b0 + lane]; }
        int j = 0;
        for (; j + 4 <= cnt; j += 4) {
            int p0 = __shfl(myp, j),     p1 = __shfl(myp, j + 1);
            int p2 = __shfl(myp, j + 2), p3 = __shfl(myp, j + 3);
            float s0 = __shfl(mys, j),     s1 = __shfl(mys, j + 1);
            float s2 = __shfl(mys, j + 2), s3 = __shfl(mys, j + 3);
            unsigned short u0 = *(const unsigned short*)(xwb + (size_t)(p0 & 0xFFFFF) * (RELS * HID) + (p0 >> 20) * HID + lane * 2);
            unsigned short u1 = *(const unsigned short*)(xwb + (size_t)(p1 & 0xFFFFF) * (RELS * HID) + (p1 >> 20) * HID + lane * 2);
            unsigned short u2 = *(const unsigned short*)(xwb + (size_t)(p2 & 0xFFFFF) * (RELS * HID) + (p2 >> 20) * HID + lane * 2);
            unsigned short u3 = *(const unsigned short*)(xwb + (size_t)(p3 & 0xFFFFF) * (RELS * HID) + (p3 >> 20) * HID + lane * 2);
            f32x2 v0 = fp8x2_2f(u0), v1 = fp8x2_2f(u1), v2 = fp8x2_2f(u2), v3 = fp8x2_2f(u3);
            ax += v0.x * s0 + v1.x * s1 + v2.x * s2 + v3.x * s3;
            ay += v0.y * s0 + v1.y * s1 + v2.y * s2 + v3.y * s3;
        }
        for (; j < cnt; ++j) {
            int p = __shfl(myp, j);
            float s = __shfl(mys, j);
            unsigned short u = *(const unsigned short*)(xwb + (size_t)(p & 0xFFFFF) * (RELS * HID) + (p >> 20) * HID + lane * 2);
            f32x2 v = fp8x2_2f(u);
            ax += v.x * s;
            ay += v.y * s;
        }
    }
    ushort2 cu = *((const ushort2*)(hnb + (size_t)node * HID) + lane);
    ushort2 o;
    o.x = f2bf(fmaxf(bf2f(cu.x) + ax, 0.f));
    o.y = f2bf(fmaxf(bf2f(cu.y) + ay, 0.f));
    *((ushort2*)(habf + (size_t)node * HID) + lane) = o;
}

// ---------------- global mean pool: sorted-batch register accumulation, flush on g-change
__global__ __launch_bounds__(256) void pool_kernel(const unsigned short* __restrict__ habf,
                                                   const int* __restrict__ batch,
                                                   float* __restrict__ psum,
                                                   float* __restrict__ pcnt) {
    int tid = threadIdx.x;
    int f = tid & 127;
    int sub = tid >> 7;
    int base = blockIdx.x * PCHUNK;
    float acc = 0.f, cnt = 0.f;
    int gcur = -1;
    for (int it = 0; it < PCHUNK / 2; ++it) {
        int node = base + it * 2 + sub;
        if (node >= NN) break;
        int g = batch[node];
        if (g != gcur) {
            if (gcur >= 0) {
                atomicAdd(&psum[gcur * HID + f], acc);
                if (f == 0) atomicAdd(&pcnt[gcur], cnt);
            }
            gcur = g; acc = 0.f; cnt = 0.f;
        }
        acc += bf2f(habf[(size_t)node * HID + f]);
        cnt += 1.f;
    }
    if (gcur >= 0) {
        atomicAdd(&psum[gcur * HID + f], acc);
        if (f == 0) atomicAdd(&pcnt[gcur], cnt);
    }
}

// ---------------- head
__global__ void head_kernel(const float* __restrict__ psum, const float* __restrict__ pcnt,
                            const float* __restrict__ g2, const float* __restrict__ b2,
                            const float* __restrict__ m2, const float* __restrict__ v2,
                            const float* __restrict__ fc1w, const float* __restrict__ fc1b,
                            const float* __restrict__ fc2w, const float* __restrict__ fc2b,
                            float* __restrict__ out) {
    __shared__ float v[HID];
    __shared__ float u[HID];
    __shared__ float lg[CLASSES];
    int j = threadIdx.x;
    float acc = 0.f;
    for (int g = 0; g < GRAPHS; ++g) {
        float val = psum[g * HID + j] / fmaxf(pcnt[g], 1.0f);
        val = (val - m2[j]) * rsqrtf(v2[j] + EPSV) * g2[j] + b2[j];
        acc += val;
    }
    v[j] = fmaxf(acc / (float)GRAPHS, 0.f);
    __syncthreads();
    float s = fc1b[j];
    for (int k = 0; k < HID; ++k) s += v[k] * fc1w[k * HID + j];
    u[j] = fmaxf(s, 0.f);
    __syncthreads();
    if (j < CLASSES) {
        float t = fc2b[j];
        for (int k = 0; k < HID; ++k) t += u[k] * fc2w[k * CLASSES + j];
        lg[j] = t;
    }
    __syncthreads();
    if (j < CLASSES) {
        float mx = lg[0];
        for (int c = 1; c < CLASSES; ++c) mx = fmaxf(mx, lg[c]);
        float se = 0.f;
        for (int c = 0; c < CLASSES; ++c) se += expf(lg[c] - mx);
        out[j] = lg[j] - mx - logf(se);
    }
}

extern "C" void kernel_launch(void* const* d_in, const int* in_sizes, int n_in,
                              void* d_out, int out_size, void* d_ws, size_t ws_size,
                              hipStream_t stream) {
    const float* x     = (const float*)d_in[0];
    const int*   ei    = (const int*)d_in[1];
    const int*   ea    = (const int*)d_in[2];
    const int*   batch = (const int*)d_in[3];
    const float* bn1g  = (const float*)d_in[4];
    const float* bn1b  = (const float*)d_in[5];
    const float* bn1m  = (const float*)d_in[6];
    const float* bn1v  = (const float*)d_in[7];
    const float* basis = (const float*)d_in[8];
    const float* comp  = (const float*)d_in[9];
    const float* root  = (const float*)d_in[10];
    const float* bias  = (const float*)d_in[11];
    const float* bn2g  = (const float*)d_in[12];
    const float* bn2b  = (const float*)d_in[13];
    const float* bn2m  = (const float*)d_in[14];
    const float* bn2v  = (const float*)d_in[15];
    const float* fc1w  = (const float*)d_in[16];
    const float* fc1b  = (const float*)d_in[17];
    const float* fc2w  = (const float*)d_in[18];
    const float* fc2b  = (const float*)d_in[19];

    float* ws = (float*)d_ws;
    size_t off = 0;
    unsigned short* wT = (unsigned short*)(ws + off); off += (size_t)LAYERS * NOUT * HID / 2;
    unsigned short* hnb  = (unsigned short*)(ws + off); off += (size_t)NN * HID / 2;
    unsigned short* habf = (unsigned short*)(ws + off); off += (size_t)NN * HID / 2;
    float* deg    = ws + off; off += (size_t)NN * RELS;
    float* psum   = ws + off; off += (size_t)GRAPHS * HID + GRAPHS;
    float* pcnt   = psum + GRAPHS * HID;
    float* escale = ws + off; off += (size_t)NE;
    int* degi     = (int*)(ws + off); off += (size_t)NN;
    int* rowptr   = (int*)(ws + off); off += (size_t)NN + 1;
    int* fillcnt  = (int*)(ws + off); off += (size_t)NN;
    int* bsum     = (int*)(ws + off); off += (size_t)SCAN_NBLK;
    int* epk      = (int*)(ws + off); off += (size_t)NE;
    off = (off + 3) & ~(size_t)3;
    unsigned char* xwb = (unsigned char*)(ws + off);
    off += (size_t)NN * RELS * HID / 4;                 // fp8: 51.2 MB
    if (ws_size < off * sizeof(float)) return;

    hipMemsetAsync(psum, 0, (GRAPHS * HID + GRAPHS) * sizeof(float), stream);
    hipMemsetAsync(deg, 0, (size_t)NN * RELS * sizeof(float), stream);
    hipMemsetAsync(fillcnt, 0, (size_t)NN * sizeof(int), stream);

    build_wcat<<<LAYERS * 64, 256, 0, stream>>>(basis, comp, root, wT);
    bn1_kernel<<<(NN * HID + 255) / 256, 256, 0, stream>>>(x, bn1g, bn1b, bn1m, bn1v, habf);

    deg_kernel<<<(NE + 255) / 256, 256, 0, stream>>>(ei, ea, deg);
    invdeg_kernel<<<(NN + 255) / 256, 256, 0, stream>>>(deg, degi);
    scan_partial<<<SCAN_NBLK, 256, 0, stream>>>(degi, rowptr, bsum);
    scan_bsum<<<1, 64, 0, stream>>>(bsum);
    scan_add<<<(NN + 255) / 256, 256, 0, stream>>>(rowptr, bsum);
    fill_kernel<<<(NE + 255) / 256, 256, 0, stream>>>(ei, ea, rowptr, deg, fillcnt, epk, escale);

    for (int l = 0; l < LAYERS; ++l) {
        gemm_mfma<<<(NN + 63) / 64, 256, 0, stream>>>(habf, wT + (size_t)l * NOUT * HID,
                                                      bias + (size_t)l * HID, hnb, xwb);
        aggregate_kernel<<<(NN + 3) / 4, 256, 0, stream>>>(rowptr, epk, escale, xwb, hnb, habf);
    }

    pool_kernel<<<(NN + PCHUNK - 1) / PCHUNK, 256, 0, stream>>>(habf, batch, psum, pcnt);
    head_kernel<<<1, 128, 0, stream>>>(psum, pcnt, bn2g, bn2b, bn2m, bn2v,
                                       fc1w, fc1b, fc2w, fc2b, (float*)d_out);
}